// Round 15
// baseline (290.899 us; speedup 1.0000x reference)
//
#include <hip/hip_runtime.h>
#include <hip/hip_bf16.h>
#include <math.h>

#define N_NODES 60000
#define E_EDGES 200000
#define DIM     128
#define NINPK   256
#define TSTEPS  6
#define LLAYERS 2
#define BGRAPH  16
#define NBINS   (TSTEPS * N_NODES)          // 360000
#define NB      ((NBINS + 1023) / 1024)     // 352 scan blocks
#define NWORDS  15000

#define B_INITP  ((NBINS + 255) / 256)          // 1407
#define B_PREP   16
#define B_HIST   ((E_EDGES + 255) / 256)        // 782
#define B_TGEMM  ((NWORDS + 127) / 128)         // 118
#define B_PLACE2 ((E_EDGES + 1023) / 1024)      // 196 (512 thr, 2 edges/thr)
#define B_EMBED  512
#define B_LSTM5  64                             // 4 cols/block @512 thr
#define GB32     ((N_NODES + 31) / 32)          // 1875 (dyn early-exit on nseg)
#define B_ZZ     64
#define B_SEGMAX ((N_NODES + 127) / 128)        // 469

typedef float f32x4 __attribute__((ext_vector_type(4)));
typedef short s16x8 __attribute__((ext_vector_type(8)));
typedef short s16x4 __attribute__((ext_vector_type(4)));

static __device__ __forceinline__ float sigm(float x) { return 1.f / (1.f + expf(-x)); }

static __device__ __forceinline__ short f2bf(float f) {
  unsigned u = __float_as_uint(f);
  u += 0x7FFFu + ((u >> 16) & 1u);
  return (short)(u >> 16);
}
static __device__ __forceinline__ float bf2f(short s) {
  return __uint_as_float(((unsigned)(unsigned short)s) << 16);
}
static __device__ __forceinline__ unsigned fenc(float f) {
  unsigned u = __float_as_uint(f);
  return (u & 0x80000000u) ? ~u : (u | 0x80000000u);
}
static __device__ __forceinline__ float fdec(unsigned u) {
  u = (u & 0x80000000u) ? (u & 0x7fffffffu) : ~u;
  return __uint_as_float(u);
}

// ============ device bodies ============

// ---- 256-thread GEMM compute+epi (table GEMM only) ----
template <bool RELU, bool BIAS, bool GOUT>
static __device__ __forceinline__ void gemm_compute_epi256(
    f32x4 (&acc)[2][8], const short* WtKt, const float* bias, short* C16,
    const int* dstmap, int N, int n0, const short* As, int rsg, int ktg,
    short* Ws, bool last) {
  const int tid = threadIdx.x;
  const int lane = tid & 63;
  const int w = tid >> 6;
  __syncthreads();
  const int4* wg = reinterpret_cast<const int4*>(WtKt);
  int4* wl = reinterpret_cast<int4*>(Ws);
#pragma unroll
  for (int p = 0; p < 4; ++p) wl[p * 256 + tid] = wg[p * 256 + tid];
  __syncthreads();
#pragma unroll
  for (int kk = 0; kk < 2; ++kk) {
    int gb = kk * 4 + (lane >> 4);
    s16x8 a[2];
#pragma unroll
    for (int fr = 0; fr < 2; ++fr) {
      int row = w * 32 + fr * 16 + (lane & 15);
      a[fr] = *(const s16x8*)&As[(row * rsg + ktg + (gb ^ (row & 7))) * 8];
    }
#pragma unroll
    for (int fc = 0; fc < 8; ++fc) {
      int col = fc * 16 + (lane & 15);
      s16x8 b = *(const s16x8*)&Ws[(col * 8 + (gb ^ (col & 7))) * 8];
      acc[0][fc] = __builtin_amdgcn_mfma_f32_16x16x32_bf16(a[0], b, acc[0][fc], 0, 0, 0);
      acc[1][fc] = __builtin_amdgcn_mfma_f32_16x16x32_bf16(a[1], b, acc[1][fc], 0, 0, 0);
    }
  }
  if (!last) return;
  const int cb = lane & 15;
  const int rb = w * 32 + (lane >> 4) * 4;
#pragma unroll
  for (int fr = 0; fr < 2; ++fr) {
#pragma unroll
    for (int reg = 0; reg < 4; ++reg) {
      int n = n0 + rb + fr * 16 + reg;
      if (n >= N) continue;
      long drow = GOUT ? (long)dstmap[n] : (long)n;
      short* cp = C16 + drow * DIM;
#pragma unroll
      for (int fc = 0; fc < 8; ++fc) {
        float x = acc[fr][fc][reg];
        if (BIAS) x += bias[fc * 16 + cb];
        if (RELU) x = fmaxf(x, 0.f);
        cp[fc * 16 + cb] = f2bf(x);
      }
    }
  }
}

// ---- 512-thread fused segscatter+GEMM, 32-row tile ----
// staging: exactly ONE chain per thread (32 segs x 16 slices = 512) -> maximal
// latency overlap across the wavefront. As2 = 32x128 bf16 (8 KB).
// MFMA: 8 waves = 2 row-bands x 4 column-quarters, acc[2].
template <bool PACKEDIN, bool GOUT>
static __device__ __forceinline__ void fusedgemm32(
    const int* __restrict__ ss, const int* __restrict__ sl,
    const int2* __restrict__ sedge, const short* __restrict__ IN16,
    const int* __restrict__ ro, const short* __restrict__ Wt,
    short* __restrict__ C16, const int* __restrict__ sd,
    const int* __restrict__ nsegp, short* As2, short* Ws, int bid) {
  const int N = nsegp[0];
  const int n0 = bid * 32;
  if (n0 >= N) return;
  const int tid = threadIdx.x;        // 0..511
  const int lane16 = tid & 15;
  const int row = tid >> 4;           // 0..31 (segment within tile)
  // Ws prefetch (both k-tiles) into regs — independent of scatter chain
  int4 wr00, wr01, wr10, wr11;
  {
    const int4* wg0 = reinterpret_cast<const int4*>(Wt);
    const int4* wg1 = reinterpret_cast<const int4*>(Wt + 128 * 64);
    wr00 = wg0[tid]; wr01 = wg0[512 + tid];
    wr10 = wg1[tid]; wr11 = wg1[512 + tid];
  }
  // single scatter chain
  int seg = n0 + row;
  bool ok = seg < N;
  int st = ok ? ss[seg] : 0;
  int ln = ok ? sl[seg] : 0;
  int2 e0 = ln ? sedge[st] : make_int2(0, 0);
  int r0 = ln ? (PACKEDIN ? ro[e0.x] : e0.x) : -1;
  s16x8 h0 = {};
  if (r0 >= 0) h0 = *(const s16x8*)&IN16[(long)r0 * DIM + lane16 * 8];
  float a0 = 0, a1 = 0, a2 = 0, a3 = 0, a4 = 0, a5 = 0, a6 = 0, a7 = 0;
  if (ln && r0 >= 0) {
    float w = __int_as_float(e0.y);
    a0 = w * bf2f(h0[0]); a1 = w * bf2f(h0[1]);
    a2 = w * bf2f(h0[2]); a3 = w * bf2f(h0[3]);
    a4 = w * bf2f(h0[4]); a5 = w * bf2f(h0[5]);
    a6 = w * bf2f(h0[6]); a7 = w * bf2f(h0[7]);
  }
  for (int e = st + 1; e < st + ln; ++e) {
    int2 v = sedge[e];
    int r2 = PACKEDIN ? ro[v.x] : v.x;
    if (PACKEDIN && r2 < 0) continue;
    float w = __int_as_float(v.y);
    s16x8 hv = *(const s16x8*)&IN16[(long)r2 * DIM + lane16 * 8];
    a0 = fmaf(w, bf2f(hv[0]), a0); a1 = fmaf(w, bf2f(hv[1]), a1);
    a2 = fmaf(w, bf2f(hv[2]), a2); a3 = fmaf(w, bf2f(hv[3]), a3);
    a4 = fmaf(w, bf2f(hv[4]), a4); a5 = fmaf(w, bf2f(hv[5]), a5);
    a6 = fmaf(w, bf2f(hv[6]), a6); a7 = fmaf(w, bf2f(hv[7]), a7);
  }
  s16x8 outv;
  outv[0] = f2bf(a0); outv[1] = f2bf(a1); outv[2] = f2bf(a2); outv[3] = f2bf(a3);
  outv[4] = f2bf(a4); outv[5] = f2bf(a5); outv[6] = f2bf(a6); outv[7] = f2bf(a7);
  int slot = (lane16 & 8) | ((lane16 & 7) ^ (row & 7));
  *(s16x8*)&As2[(row * 16 + slot) * 8] = outv;
  // Ws kt0 to LDS (regs already loaded)
  int4* wl = reinterpret_cast<int4*>(Ws);
  wl[tid] = wr00; wl[512 + tid] = wr01;
  const int lane = tid & 63;
  const int w = tid >> 6;             // 0..7
  const int rh = w & 1;               // 16-row band
  const int ch = w >> 1;              // column quarter (32 cols)
  f32x4 acc[2] = {};
#pragma unroll
  for (int kt = 0; kt < 2; ++kt) {
    __syncthreads();                  // As2 + Ws(kt) visible
#pragma unroll
    for (int kk = 0; kk < 2; ++kk) {
      int gb = kk * 4 + (lane >> 4);
      int arow = rh * 16 + (lane & 15);
      s16x8 a = *(const s16x8*)&As2[(arow * 16 + kt * 8 + (gb ^ (arow & 7))) * 8];
#pragma unroll
      for (int fc = 0; fc < 2; ++fc) {
        int col = ch * 32 + fc * 16 + (lane & 15);
        s16x8 b = *(const s16x8*)&Ws[(col * 8 + (gb ^ (col & 7))) * 8];
        acc[fc] = __builtin_amdgcn_mfma_f32_16x16x32_bf16(a, b, acc[fc], 0, 0, 0);
      }
    }
    if (kt == 0) {
      __syncthreads();                // Ws reads done before overwrite
      wl[tid] = wr10; wl[512 + tid] = wr11;
    }
  }
  // epilogue: C/D layout col=lane&15, row=(lane>>4)*4+reg  [m89-verified]
  const int cb = lane & 15;
  const int rb = rh * 16 + (lane >> 4) * 4;
#pragma unroll
  for (int reg = 0; reg < 4; ++reg) {
    int n = n0 + rb + reg;
    if (n >= N) continue;
    long drow = GOUT ? (long)sd[n] : (long)n;
    short* cp = C16 + drow * DIM;
#pragma unroll
    for (int fc = 0; fc < 2; ++fc) {
      float x = fmaxf(acc[fc][reg], 0.f);
      cp[ch * 32 + fc * 16 + cb] = f2bf(x);
    }
  }
}

// table GEMM (256 thr): table16[w] = wemb[w] @ WtAd + adb
static __device__ __forceinline__ void tablegemm_body(
    const float* __restrict__ Af, const short* __restrict__ Wt,
    const float* __restrict__ bias, short* __restrict__ table16, short* As,
    short* Ws, int bid) {
  const int n0 = bid * 128;
  const int tid = threadIdx.x;
  f32x4 acc[2][8] = {};
#pragma unroll
  for (int kt = 0; kt < 4; ++kt) {
    __syncthreads();
#pragma unroll
    for (int p = 0; p < 4; ++p) {
      int gi = p * 256 + tid;
      int row = gi >> 3, s = gi & 7;
      int n = n0 + row;
      s16x8 v = {};
      if (n < NWORDS) {
        const float* ap = Af + (long)n * NINPK + kt * 64 + (s ^ (row & 7)) * 8;
        float4 v0 = *reinterpret_cast<const float4*>(ap);
        float4 v1 = *reinterpret_cast<const float4*>(ap + 4);
        v[0] = f2bf(v0.x); v[1] = f2bf(v0.y); v[2] = f2bf(v0.z); v[3] = f2bf(v0.w);
        v[4] = f2bf(v1.x); v[5] = f2bf(v1.y); v[6] = f2bf(v1.z); v[7] = f2bf(v1.w);
      }
      *(s16x8*)&As[(row * 8 + s) * 8] = v;
    }
    gemm_compute_epi256<false, true, false>(acc, Wt + kt * 128 * 64, bias, table16,
                                            nullptr, NWORDS, n0, As, 8, 0, Ws,
                                            kt == 3);
  }
}

// zero src-only touched hb rows (512 thr, 16B/lane)
static __device__ __forceinline__ void zzero_body(short* __restrict__ hb,
                                                  const int* __restrict__ zl,
                                                  const int* __restrict__ nzp,
                                                  int bid, int nblocks) {
  int nz = nzp[0];
  int l = threadIdx.x & 15;
  s16x8 z = {};
  for (int s = bid * 32 + (threadIdx.x >> 4); s < nz; s += nblocks * 32) {
    *reinterpret_cast<s16x8*>(&hb[(long)zl[s] * DIM + l * 8]) = z;
  }
}

// fused LSTM step k (512 thr, 4 cols/block)
static __device__ __forceinline__ void lstm_body512(
    int bid, const float* __restrict__ hxc, float* __restrict__ hxn,
    float* __restrict__ cx, const float* __restrict__ Wih,
    const float* __restrict__ Whh, const float* __restrict__ bih,
    const float* __restrict__ bhh, const int* __restrict__ meta,
    short* __restrict__ WtBase, int k, float* wi, float* wh) {
  int tid = threadIdx.x;
  int i = bid >> 5;
  int j4 = bid & 31;
  int jl = tid >> 7;
  int r = tid & 127;
  int j = j4 * 4 + jl;
  float* wiL = wi + jl * 512;
  float* whL = wh + jl * 512;
#pragma unroll
  for (int g4 = 0; g4 < 4; ++g4) {
    wiL[g4 * 128 + r] = Wih[((long)i * 512 + g4 * 128 + j) * DIM + r];
    whL[g4 * 128 + r] = Whh[((long)i * 512 + g4 * 128 + j) * DIM + r];
  }
  __syncthreads();
  const float4* x4 = reinterpret_cast<const float4*>(hxc + ((long)i * DIM + r) * DIM);
  float a0 = 0, a1 = 0, a2 = 0, a3 = 0, b0 = 0, b1 = 0, b2 = 0, b3 = 0;
#pragma unroll 4
  for (int k4 = 0; k4 < 32; ++k4) {
    float4 xv = x4[k4];
    const float* vp = &xv.x;
#pragma unroll
    for (int q = 0; q < 4; ++q) {
      int kk = k4 * 4 + q;
      float xs = vp[q];
      a0 = fmaf(xs, wiL[kk], a0);       a1 = fmaf(xs, wiL[128 + kk], a1);
      a2 = fmaf(xs, wiL[256 + kk], a2); a3 = fmaf(xs, wiL[384 + kk], a3);
      b0 = fmaf(xs, whL[kk], b0);       b1 = fmaf(xs, whL[128 + kk], b1);
      b2 = fmaf(xs, whL[256 + kk], b2); b3 = fmaf(xs, whL[384 + kk], b3);
    }
  }
  int cbi = i * 512 + j;
  float g0i = a0 + bih[cbi] + bhh[cbi];
  float g0f = a1 + bih[cbi + 128] + bhh[cbi + 128];
  float g0g = a2 + bih[cbi + 256] + bhh[cbi + 256];
  float g0o = a3 + bih[cbi + 384] + bhh[cbi + 384];
  float g1i = g0i + b0, g1f = g0f + b1, g1g = g0g + b2, g1o = g0o + b3;
  int idx = i * 16384 + r * 128 + j;
  float c0v = cx[idx];
  float c_zero = sigm(g0i) * tanhf(g0g);
  float h_zero = sigm(g0o) * tanhf(c_zero);
  float c_st = sigm(g1f) * c0v + sigm(g1i) * tanhf(g1g);
  float h_st = sigm(g1o) * tanhf(c_st);
  int first = meta[8 + k];
  int has = meta[k] > 0;
  float hi_v = first ? h_st : h_zero;
  float ci_v = first ? c0v : c_zero;
  float xj = reinterpret_cast<const float*>(x4)[j];
  float hnew = has ? hi_v : xj;
  float cnew = has ? ci_v : c0v;
  hxn[idx] = hnew;
  cx[idx] = cnew;
  short* Wt = WtBase + i * 16384;
  int kb = r >> 6, g = (r >> 3) & 7, jj = r & 7;
  Wt[((kb * DIM + j) * 8 + (g ^ (j & 7))) * 8 + jj] = f2bf(hnew);
}

// ============ kernels ============

// setup0: init state/hist/flags/meta/keys + adaptW bf16 tiles
__global__ void k_setup0(const float* __restrict__ gcn, float* __restrict__ hxA,
                         float* __restrict__ cx, int* __restrict__ meta,
                         unsigned* __restrict__ keys, int* __restrict__ hist,
                         unsigned* __restrict__ flagbits,
                         const float* __restrict__ adW, short* __restrict__ WtAd) {
  int bid = blockIdx.x;
  int tid = threadIdx.x;
  if (bid < B_INITP) {
    int i = bid * 256 + tid;
    if (i < LLAYERS * DIM * DIM) { hxA[i] = gcn[i]; cx[i] = 0.f; }
    if (i < BGRAPH * DIM) keys[i] = 0u;
    if (i < 64) meta[i] = 0;
    if (i < NBINS) hist[i] = 0;
    if (i < (NBINS + 31) / 32) flagbits[i] = 0u;
  } else {
    int idx = (bid - B_INITP) * 256 + tid;  // < 4096
    int g = idx & 7;
    int c = (idx >> 3) & 127;
    int kb = idx >> 10;
    s16x8 s;
#pragma unroll
    for (int j = 0; j < 8; ++j) s[j] = f2bf(adW[(long)(kb * 64 + g * 8 + j) * DIM + c]);
    *(s16x8*)&WtAd[(((long)kb * DIM + c) * 8 + (g ^ (c & 7))) * 8] = s;
  }
}

// hist/flag atomics + table GEMM (fp32 wemb direct), 256 thr
__global__ __launch_bounds__(256) void k_histg(
    const int* __restrict__ et, const int* __restrict__ src,
    const int* __restrict__ dst, int* __restrict__ hist,
    unsigned* __restrict__ flagbits, const float* __restrict__ wemb,
    const short* __restrict__ WtAd, const float* __restrict__ adb,
    short* __restrict__ table16) {
  __shared__ short As[128 * 64];
  __shared__ short Ws[128 * 64];
  int bid = blockIdx.x;
  if (bid < B_HIST) {
    int e = bid * 256 + threadIdx.x;
    if (e < E_EDGES) {
      int t = et[e];
      atomicAdd(&hist[t * N_NODES + dst[e]], 1);
      int fs = t * N_NODES + src[e];
      atomicOr(&flagbits[fs >> 5], 1u << (fs & 31));
    }
  } else {
    tablegemm_body(wemb, WtAd, adb, table16, As, Ws, bid - B_HIST);
  }
}

// fused 2-level exclusive scan: hist values, nonempty indicator, z indicator.
// bsum arrays stay RAW (per-block sums); scan3seg re-scans them locally.
__global__ void k_scan1b(const int* __restrict__ hist,
                         const unsigned* __restrict__ flagbits,
                         int* __restrict__ scanA, int* __restrict__ scanB,
                         int* __restrict__ scanC, int* __restrict__ bsumA,
                         int* __restrict__ bsumB, int* __restrict__ bsumC) {
  __shared__ int shA[256], shB[256], shC[256];
  int b0 = blockIdx.x * 1024;
  int tid = threadIdx.x;
  int v[4], w[4], z[4];
  int sA = 0, sB = 0, sC = 0;
#pragma unroll
  for (int q = 0; q < 4; ++q) {
    int i = b0 + tid * 4 + q;
    int c = (i < NBINS) ? hist[i] : 0;
    int fl = (i < NBINS) ? (int)((flagbits[i >> 5] >> (i & 31)) & 1u) : 0;
    v[q] = c; w[q] = (c > 0) ? 1 : 0; z[q] = (fl && c == 0) ? 1 : 0;
    sA += c; sB += w[q]; sC += z[q];
  }
  shA[tid] = sA; shB[tid] = sB; shC[tid] = sC;
  __syncthreads();
  for (int off = 1; off < 256; off <<= 1) {
    int xA = (tid >= off) ? shA[tid - off] : 0;
    int xB = (tid >= off) ? shB[tid - off] : 0;
    int xC = (tid >= off) ? shC[tid - off] : 0;
    __syncthreads();
    shA[tid] += xA; shB[tid] += xB; shC[tid] += xC;
    __syncthreads();
  }
  int exA = shA[tid] - sA, exB = shB[tid] - sB, exC = shC[tid] - sC;
#pragma unroll
  for (int q = 0; q < 4; ++q) {
    int i = b0 + tid * 4 + q;
    if (i < NBINS) { scanA[i] = exA; scanB[i] = exB; scanC[i] = exC; }
    exA += v[q]; exB += w[q]; exC += z[q];
  }
  if (tid == 255) {
    bsumA[blockIdx.x] = shA[255];
    bsumB[blockIdx.x] = shB[255];
    bsumC[blockIdx.x] = shC[255];
  }
}

// scan finalize + segment build + meta (scanA/B/C immutable, cursor -> scanD)
__global__ __launch_bounds__(256) void k_scan3seg(
    const int* __restrict__ scanA, const int* __restrict__ bsumA,
    const int* __restrict__ scanB, const int* __restrict__ bsumB,
    const int* __restrict__ scanC, const int* __restrict__ bsumC,
    const int* __restrict__ hist, const unsigned* __restrict__ flagbits,
    int* __restrict__ scanD, int* __restrict__ segdst, int* __restrict__ segstart,
    int* __restrict__ seglen, int* __restrict__ rowof, int* __restrict__ zlist,
    int* __restrict__ meta) {
  __shared__ int sA[512], sB[512], sC[512];
  int tid = threadIdx.x;
  for (int q = tid; q < 512; q += 256) {
    sA[q] = (q < NB) ? bsumA[q] : 0;
    sB[q] = (q < NB) ? bsumB[q] : 0;
    sC[q] = (q < NB) ? bsumC[q] : 0;
  }
  __syncthreads();
  for (int off = 1; off < 512; off <<= 1) {
    int q0 = tid, q1 = tid + 256;
    int a0 = (q0 >= off) ? sA[q0 - off] : 0, b0 = (q0 >= off) ? sB[q0 - off] : 0,
        c0 = (q0 >= off) ? sC[q0 - off] : 0;
    int a1 = (q1 >= off) ? sA[q1 - off] : 0, b1 = (q1 >= off) ? sB[q1 - off] : 0,
        c1 = (q1 >= off) ? sC[q1 - off] : 0;
    __syncthreads();
    sA[q0] += a0; sB[q0] += b0; sC[q0] += c0;
    sA[q1] += a1; sB[q1] += b1; sC[q1] += c1;
    __syncthreads();
  }
  int i = blockIdx.x * 256 + tid;
  if (i < NBINS) {
    int blk = i >> 10;
    int eAx = blk ? sA[blk - 1] : 0;
    int eBx = blk ? sB[blk - 1] : 0;
    int eCx = blk ? sC[blk - 1] : 0;
    int t = i / N_NODES;
    int tb = t * N_NODES;
    int blkT = tb >> 10;
    int vA = scanA[i] + eAx;
    scanD[i] = vA;
    int c = hist[i];
    if (c > 0) {
      int baseB = scanB[tb] + (blkT ? sB[blkT - 1] : 0);
      int sidx = scanB[i] + eBx - baseB;
      long sb = (long)tb + sidx;
      segdst[sb] = i - tb;
      segstart[sb] = vA;
      seglen[sb] = c;
      rowof[i] = sidx;
    } else {
      rowof[i] = -1;
      if ((flagbits[i >> 5] >> (i & 31)) & 1u) {
        int baseC = scanC[tb] + (blkT ? sC[blkT - 1] : 0);
        int zr = scanC[i] + eCx - baseC;
        zlist[(long)tb + zr] = i - tb;
      }
    }
  }
  if (blockIdx.x == 0 && tid == 0) {
    int loA[TSTEPS + 1], loB[TSTEPS + 1], loC[TSTEPS + 1];
    for (int t = 0; t < TSTEPS; ++t) {
      int ib = t * N_NODES, blk = ib >> 10;
      loA[t] = scanA[ib] + (blk ? sA[blk - 1] : 0);
      loB[t] = scanB[ib] + (blk ? sB[blk - 1] : 0);
      loC[t] = scanC[ib] + (blk ? sC[blk - 1] : 0);
    }
    loA[TSTEPS] = sA[NB - 1]; loB[TSTEPS] = sB[NB - 1]; loC[TSTEPS] = sC[NB - 1];
    int f = 0;
    for (int t = 0; t < TSTEPS; ++t) {
      int cnt = loA[t + 1] - loA[t];
      meta[t] = cnt;
      meta[8 + t] = f; f |= (cnt > 0);
      meta[32 + t] = loB[t + 1] - loB[t];   // segcnt
      meta[40 + t] = loC[t + 1] - loC[t];   // zcnt
    }
  }
}

// setup1 (512 thr): place edges (2/thread) + embed gather + lstm(0)
__global__ __launch_bounds__(512) void k_setup1(
    const int* __restrict__ et, const int* __restrict__ src,
    const int* __restrict__ dst, const float* __restrict__ ew,
    int* __restrict__ scanD, int2* __restrict__ sedge,
    const short* __restrict__ table16, const int* __restrict__ wid,
    short* __restrict__ hb, const float* __restrict__ hxA, float* __restrict__ hxB,
    float* __restrict__ cx, const float* __restrict__ Wih,
    const float* __restrict__ Whh, const float* __restrict__ bih,
    const float* __restrict__ bhh, const int* __restrict__ meta,
    short* __restrict__ WtT) {
  __shared__ float lb[4096];
  int bid = blockIdx.x;
  int tid = threadIdx.x;
  if (bid < B_PLACE2) {
    int e0 = bid * 1024 + tid;
    int e1 = e0 + 512;
    bool ok0 = e0 < E_EDGES, ok1 = e1 < E_EDGES;
    int t0 = ok0 ? et[e0] : 0, t1 = ok1 ? et[e1] : 0;
    int d0 = ok0 ? dst[e0] : 0, d1 = ok1 ? dst[e1] : 0;
    int s0 = ok0 ? src[e0] : 0, s1 = ok1 ? src[e1] : 0;
    float w0 = ok0 ? ew[e0] : 0.f, w1 = ok1 ? ew[e1] : 0.f;
    int p0 = ok0 ? atomicAdd(&scanD[t0 * N_NODES + d0], 1) : 0;
    int p1 = ok1 ? atomicAdd(&scanD[t1 * N_NODES + d1], 1) : 0;
    if (ok0) sedge[p0] = make_int2(s0, __float_as_int(w0));
    if (ok1) sedge[p1] = make_int2(s1, __float_as_int(w1));
  } else if (bid < B_PLACE2 + B_EMBED) {
    int l = tid & 15;
    for (int n = (bid - B_PLACE2) * 32 + (tid >> 4); n < N_NODES; n += B_EMBED * 32) {
      *reinterpret_cast<s16x8*>(&hb[(long)n * DIM + l * 8]) =
          *reinterpret_cast<const s16x8*>(&table16[(long)wid[n] * DIM + l * 8]);
    }
  } else {
    lstm_body512(bid - B_PLACE2 - B_EMBED, hxA, hxB, cx, Wih, Whh, bih, bhh, meta,
                 WtT, 0, lb, lb + 2048);
  }
}

// loop launch A (512 thr): fused scat0+gemm0 ∥ lstm(t+1)
__global__ __launch_bounds__(512) void k_A(
    const int* __restrict__ ss, const int* __restrict__ sl,
    const int2* __restrict__ sedge, const short* __restrict__ hb,
    const short* __restrict__ Wt0, short* __restrict__ P2b,
    const int* __restrict__ nsegp, const float* __restrict__ hxc,
    float* __restrict__ hxn, float* __restrict__ cx,
    const float* __restrict__ Wih, const float* __restrict__ Whh,
    const float* __restrict__ bih, const float* __restrict__ bhh,
    const int* __restrict__ meta, short* __restrict__ WtNext, int k) {
  __shared__ short As2[32 * 128];
  __shared__ short Ws[128 * 64];
  int bid = blockIdx.x;
  if (bid < GB32) {
    fusedgemm32<false, false>(ss, sl, sedge, hb, nullptr, Wt0, P2b, nullptr,
                              nsegp, As2, Ws, bid);
  } else if (k < TSTEPS) {
    __shared__ float lb2[2048];
    float* lb = (float*)Ws;
    lstm_body512(bid - GB32, hxc, hxn, cx, Wih, Whh, bih, bhh, meta, WtNext, k,
                 lb, lb2);
  }
}

// loop launch B (512 thr): fused scat1+gemm1 ∥ zzero
__global__ __launch_bounds__(512) void k_B(
    const int* __restrict__ ss, const int* __restrict__ sl,
    const int2* __restrict__ sedge, const short* __restrict__ P2b,
    const int* __restrict__ ro, const short* __restrict__ Wt1,
    short* __restrict__ hb, const int* __restrict__ sd,
    const int* __restrict__ nsegp, const int* __restrict__ zl,
    const int* __restrict__ nzp) {
  __shared__ short As2[32 * 128];
  __shared__ short Ws[128 * 64];
  int bid = blockIdx.x;
  if (bid < GB32) {
    fusedgemm32<true, true>(ss, sl, sedge, P2b, ro, Wt1, hb, sd, nsegp,
                            As2, Ws, bid);
  } else {
    zzero_body(hb, zl, nzp, bid - GB32, B_ZZ);
  }
}

// segment max: vectorized 16B loads, LDS tree reduce, atomicMax only, no fences
__global__ __launch_bounds__(256) void k_segmax(
    const short* __restrict__ hb, const int* __restrict__ gid,
    unsigned* __restrict__ keys) {
  __shared__ float red[256 * 8];
  int tid = threadIdx.x;
  int c = tid & 15;
  int r = tid >> 4;
  int n0 = blockIdx.x * 128;
  int nend = min(n0 + 128, N_NODES);
  float m[8];
#pragma unroll
  for (int j = 0; j < 8; ++j) m[j] = -INFINITY;
  if (gid[n0] == gid[nend - 1]) {
    int g = gid[n0];
#pragma unroll
    for (int it = 0; it < 8; ++it) {
      int n = n0 + it * 16 + r;
      if (n < N_NODES) {
        s16x8 v = *(const s16x8*)&hb[(long)n * DIM + c * 8];
#pragma unroll
        for (int j = 0; j < 8; ++j) m[j] = fmaxf(m[j], bf2f(v[j]));
      }
    }
#pragma unroll
    for (int j = 0; j < 8; ++j) red[tid * 8 + j] = m[j];
    __syncthreads();
    for (int off = 8; off >= 1; off >>= 1) {
      if (r < off) {
#pragma unroll
        for (int j = 0; j < 8; ++j)
          red[tid * 8 + j] = fmaxf(red[tid * 8 + j], red[(tid + off * 16) * 8 + j]);
      }
      __syncthreads();
    }
    if (r == 0) {
#pragma unroll
      for (int j = 0; j < 8; ++j)
        atomicMax(&keys[(long)g * DIM + c * 8 + j], fenc(red[tid * 8 + j]));
    }
  } else {
    int curg = -1;
#pragma unroll
    for (int it = 0; it < 8; ++it) {
      int n = n0 + it * 16 + r;
      if (n >= N_NODES) break;
      int g = gid[n];
      if (g != curg) {
        if (curg >= 0) {
#pragma unroll
          for (int j = 0; j < 8; ++j)
            atomicMax(&keys[(long)curg * DIM + c * 8 + j], fenc(m[j]));
        }
        curg = g;
#pragma unroll
        for (int j = 0; j < 8; ++j) m[j] = -INFINITY;
      }
      s16x8 v = *(const s16x8*)&hb[(long)n * DIM + c * 8];
#pragma unroll
      for (int j = 0; j < 8; ++j) m[j] = fmaxf(m[j], bf2f(v[j]));
    }
    if (curg >= 0) {
#pragma unroll
      for (int j = 0; j < 8; ++j)
        atomicMax(&keys[(long)curg * DIM + c * 8 + j], fenc(m[j]));
    }
  }
}

// final: logits, probs, BCE loss
__global__ void k_final(const unsigned* __restrict__ keys, const float* __restrict__ outW,
                        const float* __restrict__ outB, const float* __restrict__ y,
                        float* __restrict__ out) {
  __shared__ float lt[BGRAPH];
  int tid = threadIdx.x;
  int b = tid >> 2, l4 = tid & 3;
  float s = 0.f;
  for (int d = l4; d < DIM; d += 4) {
    float v = fdec(keys[(long)b * DIM + d]);
    if (!isfinite(v)) v = 0.f;
    s += v * outW[d];
  }
  s += __shfl_down(s, 1);
  s += __shfl_down(s, 2);
  if (l4 == 0) {
    float l = s + outB[0];
    out[1 + b] = 1.f / (1.f + expf(-l));
    lt[b] = fmaxf(l, 0.f) - l * y[b] + log1pf(expf(-fabsf(l)));
  }
  __syncthreads();
  if (tid == 0) {
    float acc = 0.f;
    for (int i = 0; i < BGRAPH; ++i) acc += lt[i];
    out[0] = acc / (float)BGRAPH;
  }
}

extern "C" void kernel_launch(void* const* d_in, const int* in_sizes, int n_in,
                              void* d_out, int out_size, void* d_ws, size_t ws_size,
                              hipStream_t stream) {
  const int* word_ids = (const int*)d_in[0];
  const int* src = (const int*)d_in[1];
  const int* dst = (const int*)d_in[2];
  const int* et = (const int*)d_in[3];
  const float* ew = (const float*)d_in[4];
  const int* gid = (const int*)d_in[5];
  const float* y = (const float*)d_in[6];
  const float* wemb = (const float*)d_in[7];
  const float* adW = (const float*)d_in[8];
  const float* adb = (const float*)d_in[9];
  const float* gcn = (const float*)d_in[10];
  const float* Wih = (const float*)d_in[11];
  const float* Whh = (const float*)d_in[12];
  const float* bih = (const float*)d_in[13];
  const float* bhh = (const float*)d_in[14];
  const float* outW = (const float*)d_in[15];
  const float* outB = (const float*)d_in[16];
  float* out = (float*)d_out;

  char* ws = (char*)d_ws;
  const long ND = (long)N_NODES * DIM;
  short* hb = (short*)ws;       ws += ND * 2;
  short* P2b = (short*)ws;      ws += ND * 2;
  float* hxA = (float*)ws;      ws += LLAYERS * DIM * DIM * 4;
  float* hxB = (float*)ws;      ws += LLAYERS * DIM * DIM * 4;
  float* cx = (float*)ws;       ws += LLAYERS * DIM * DIM * 4;
  int* meta = (int*)ws;         ws += 64 * 4;
  unsigned* keys = (unsigned*)ws; ws += BGRAPH * DIM * 4;
  int* hist = (int*)ws;         ws += (long)NBINS * 4;
  int* scanA = (int*)ws;        ws += (long)NBINS * 4;
  int* scanB = (int*)ws;        ws += (long)NBINS * 4;
  int* scanC = (int*)ws;        ws += (long)NBINS * 4;
  int* scanD = (int*)ws;        ws += (long)NBINS * 4;
  int* bsumA = (int*)ws;        ws += ((NB + 63) & ~63) * 4;
  int* bsumB = (int*)ws;        ws += ((NB + 63) & ~63) * 4;
  int* bsumC = (int*)ws;        ws += ((NB + 63) & ~63) * 4;
  int* rowof = (int*)ws;        ws += (long)NBINS * 4;
  int* segdst = (int*)ws;       ws += (long)NBINS * 4;
  int* segstart = (int*)ws;     ws += (long)NBINS * 4;
  int* seglen = (int*)ws;       ws += (long)NBINS * 4;
  int* zlist = (int*)ws;        ws += (long)NBINS * 4;
  int2* sedge = (int2*)ws;      ws += (long)E_EDGES * 8;
  unsigned* flagbits = (unsigned*)ws; ws += ((NBINS + 31) / 32 + 64) * 4;
  short* table16 = (short*)ws;  ws += (long)NWORDS * DIM * 2;
  short* WtAd = (short*)ws;     ws += 4L * DIM * 64 * 2;
  short* WtT = (short*)ws;      ws += 7L * 2 * 16384 * 2;  // [t][layer] bf16 tiles

  // ---- setup (5 launches) ----
  k_setup0<<<B_INITP + B_PREP, 256, 0, stream>>>(gcn, hxA, cx, meta, keys, hist,
                                                 flagbits, adW, WtAd);
  k_histg<<<B_HIST + B_TGEMM, 256, 0, stream>>>(et, src, dst, hist, flagbits,
                                                wemb, WtAd, adb, table16);
  k_scan1b<<<NB, 256, 0, stream>>>(hist, flagbits, scanA, scanB, scanC,
                                   bsumA, bsumB, bsumC);
  k_scan3seg<<<B_INITP, 256, 0, stream>>>(scanA, bsumA, scanB, bsumB, scanC, bsumC,
                                          hist, flagbits, scanD, segdst, segstart,
                                          seglen, rowof, zlist, meta);
  k_setup1<<<B_PLACE2 + B_EMBED + B_LSTM5, 512, 0, stream>>>(
      et, src, dst, ew, scanD, sedge, table16, word_ids, hb, hxA, hxB, cx,
      Wih, Whh, bih, bhh, meta, WtT);

  // ---- t-loop (2 launches per step) ----
  for (int t = 0; t < TSTEPS; ++t) {
    const int* nsegp = &meta[32 + t];
    const int* nzp = &meta[40 + t];
    const int* ss = segstart + (long)t * N_NODES;
    const int* sl = seglen + (long)t * N_NODES;
    const int* sd = segdst + (long)t * N_NODES;
    const int* ro = rowof + (long)t * N_NODES;
    const int* zl = zlist + (long)t * N_NODES;
    int k = t + 1;  // prefetched lstm step
    const float* hxc = (k & 1) ? hxB : hxA;
    float* hxn = (k & 1) ? hxA : hxB;
    k_A<<<GB32 + B_LSTM5, 512, 0, stream>>>(
        ss, sl, sedge, hb, WtT + (long)t * 2 * 16384, P2b, nsegp,
        hxc, hxn, cx, Wih, Whh, bih, bhh, meta, WtT + (long)k * 2 * 16384, k);
    k_B<<<GB32 + B_ZZ, 512, 0, stream>>>(
        ss, sl, sedge, P2b, ro, WtT + ((long)t * 2 + 1) * 16384, hb, sd, nsegp,
        zl, nzp);
  }

  k_segmax<<<B_SEGMAX, 256, 0, stream>>>(hb, gid, keys);
  k_final<<<1, 64, 0, stream>>>(keys, outW, outB, y, out);
}

// Round 16
// 274.618 us; speedup vs baseline: 1.0593x; 1.0593x over previous
//
#include <hip/hip_runtime.h>
#include <hip/hip_bf16.h>
#include <math.h>

#define N_NODES 60000
#define E_EDGES 200000
#define DIM     128
#define NINPK   256
#define TSTEPS  6
#define LLAYERS 2
#define BGRAPH  16
#define NBINS   (TSTEPS * N_NODES)          // 360000
#define NB      ((NBINS + 1023) / 1024)     // 352 scan blocks
#define NWORDS  15000

#define B_INITP  ((NBINS + 255) / 256)          // 1407
#define B_PREP   16
#define B_HIST   ((E_EDGES + 255) / 256)        // 782
#define B_TGEMM  ((NWORDS + 127) / 128)         // 118
#define B_PLACE2 ((E_EDGES + 1023) / 1024)      // 196 (512 thr, 2 edges/thr)
#define B_EMBED  512
#define B_LSTM5  64                             // 4 cols/block @512 thr
#define GB64     ((N_NODES + 63) / 64)          // 938 (dyn early-exit on nseg)
#define B_ZZ     64
#define B_SEGMAX ((N_NODES + 127) / 128)        // 469

typedef float f32x4 __attribute__((ext_vector_type(4)));
typedef short s16x8 __attribute__((ext_vector_type(8)));
typedef short s16x4 __attribute__((ext_vector_type(4)));

static __device__ __forceinline__ float sigm(float x) { return 1.f / (1.f + expf(-x)); }

static __device__ __forceinline__ short f2bf(float f) {
  unsigned u = __float_as_uint(f);
  u += 0x7FFFu + ((u >> 16) & 1u);
  return (short)(u >> 16);
}
static __device__ __forceinline__ float bf2f(short s) {
  return __uint_as_float(((unsigned)(unsigned short)s) << 16);
}
static __device__ __forceinline__ unsigned fenc(float f) {
  unsigned u = __float_as_uint(f);
  return (u & 0x80000000u) ? ~u : (u | 0x80000000u);
}
static __device__ __forceinline__ float fdec(unsigned u) {
  u = (u & 0x80000000u) ? (u & 0x7fffffffu) : ~u;
  return __uint_as_float(u);
}

// ============ device bodies ============

// ---- 256-thread GEMM compute+epi (table GEMM only) ----
template <bool RELU, bool BIAS, bool GOUT>
static __device__ __forceinline__ void gemm_compute_epi256(
    f32x4 (&acc)[2][8], const short* WtKt, const float* bias, short* C16,
    const int* dstmap, int N, int n0, const short* As, int rsg, int ktg,
    short* Ws, bool last) {
  const int tid = threadIdx.x;
  const int lane = tid & 63;
  const int w = tid >> 6;
  __syncthreads();
  const int4* wg = reinterpret_cast<const int4*>(WtKt);
  int4* wl = reinterpret_cast<int4*>(Ws);
#pragma unroll
  for (int p = 0; p < 4; ++p) wl[p * 256 + tid] = wg[p * 256 + tid];
  __syncthreads();
#pragma unroll
  for (int kk = 0; kk < 2; ++kk) {
    int gb = kk * 4 + (lane >> 4);
    s16x8 a[2];
#pragma unroll
    for (int fr = 0; fr < 2; ++fr) {
      int row = w * 32 + fr * 16 + (lane & 15);
      a[fr] = *(const s16x8*)&As[(row * rsg + ktg + (gb ^ (row & 7))) * 8];
    }
#pragma unroll
    for (int fc = 0; fc < 8; ++fc) {
      int col = fc * 16 + (lane & 15);
      s16x8 b = *(const s16x8*)&Ws[(col * 8 + (gb ^ (col & 7))) * 8];
      acc[0][fc] = __builtin_amdgcn_mfma_f32_16x16x32_bf16(a[0], b, acc[0][fc], 0, 0, 0);
      acc[1][fc] = __builtin_amdgcn_mfma_f32_16x16x32_bf16(a[1], b, acc[1][fc], 0, 0, 0);
    }
  }
  if (!last) return;
  const int cb = lane & 15;
  const int rb = w * 32 + (lane >> 4) * 4;
#pragma unroll
  for (int fr = 0; fr < 2; ++fr) {
#pragma unroll
    for (int reg = 0; reg < 4; ++reg) {
      int n = n0 + rb + fr * 16 + reg;
      if (n >= N) continue;
      long drow = GOUT ? (long)dstmap[n] : (long)n;
      short* cp = C16 + drow * DIM;
#pragma unroll
      for (int fc = 0; fc < 8; ++fc) {
        float x = acc[fr][fc][reg];
        if (BIAS) x += bias[fc * 16 + cb];
        if (RELU) x = fmaxf(x, 0.f);
        cp[fc * 16 + cb] = f2bf(x);
      }
    }
  }
}

// ---- 512-thread fused segscatter+GEMM, 64-row tile ----
// staging: 2 chain-iterations/thread (batched prefetch); As2 = 64x128 bf16.
// MFMA: 8 waves = 4 row-bands x 2 column halves, 4 col-frags each.
template <bool PACKEDIN, bool GOUT>
static __device__ __forceinline__ void fusedgemm64(
    const int* __restrict__ ss, const int* __restrict__ sl,
    const int2* __restrict__ sedge, const short* __restrict__ IN16,
    const int* __restrict__ ro, const short* __restrict__ Wt,
    short* __restrict__ C16, const int* __restrict__ sd,
    const int* __restrict__ nsegp, short* As2, short* Ws, int bid) {
  const int N = nsegp[0];
  const int n0 = bid * 64;
  if (n0 >= N) return;
  const int tid = threadIdx.x;        // 0..511
  const int lane16 = tid & 15;
  const int grp = tid >> 4;           // 0..31
  // Ws prefetch (both k-tiles) into regs — independent of scatter chains
  int4 wr00, wr01, wr10, wr11;
  {
    const int4* wg0 = reinterpret_cast<const int4*>(Wt);
    const int4* wg1 = reinterpret_cast<const int4*>(Wt + 128 * 64);
    wr00 = wg0[tid]; wr01 = wg0[512 + tid];
    wr10 = wg1[tid]; wr11 = wg1[512 + tid];
  }
  // batched 2-chain prefetch
  int st[2], ln[2];
#pragma unroll
  for (int it = 0; it < 2; ++it) {
    int seg = n0 + it * 32 + grp;
    bool ok = seg < N;
    st[it] = ok ? ss[seg] : 0;
    ln[it] = ok ? sl[seg] : 0;
  }
  int2 e0[2];
#pragma unroll
  for (int it = 0; it < 2; ++it)
    e0[it] = ln[it] ? sedge[st[it]] : make_int2(0, 0);
  int r0[2];
#pragma unroll
  for (int it = 0; it < 2; ++it)
    r0[it] = ln[it] ? (PACKEDIN ? ro[e0[it].x] : e0[it].x) : -1;
  s16x8 h0[2];
#pragma unroll
  for (int it = 0; it < 2; ++it) {
    s16x8 z = {};
    h0[it] = (r0[it] >= 0) ? *(const s16x8*)&IN16[(long)r0[it] * DIM + lane16 * 8] : z;
  }
#pragma unroll
  for (int it = 0; it < 2; ++it) {
    int row = it * 32 + grp;
    float a0 = 0, a1 = 0, a2 = 0, a3 = 0, a4 = 0, a5 = 0, a6 = 0, a7 = 0;
    if (ln[it] && r0[it] >= 0) {
      float w = __int_as_float(e0[it].y);
      a0 = w * bf2f(h0[it][0]); a1 = w * bf2f(h0[it][1]);
      a2 = w * bf2f(h0[it][2]); a3 = w * bf2f(h0[it][3]);
      a4 = w * bf2f(h0[it][4]); a5 = w * bf2f(h0[it][5]);
      a6 = w * bf2f(h0[it][6]); a7 = w * bf2f(h0[it][7]);
    }
    for (int e = st[it] + 1; e < st[it] + ln[it]; ++e) {
      int2 v = sedge[e];
      int r2 = PACKEDIN ? ro[v.x] : v.x;
      if (PACKEDIN && r2 < 0) continue;
      float w = __int_as_float(v.y);
      s16x8 hv = *(const s16x8*)&IN16[(long)r2 * DIM + lane16 * 8];
      a0 = fmaf(w, bf2f(hv[0]), a0); a1 = fmaf(w, bf2f(hv[1]), a1);
      a2 = fmaf(w, bf2f(hv[2]), a2); a3 = fmaf(w, bf2f(hv[3]), a3);
      a4 = fmaf(w, bf2f(hv[4]), a4); a5 = fmaf(w, bf2f(hv[5]), a5);
      a6 = fmaf(w, bf2f(hv[6]), a6); a7 = fmaf(w, bf2f(hv[7]), a7);
    }
    s16x8 outv;
    outv[0] = f2bf(a0); outv[1] = f2bf(a1); outv[2] = f2bf(a2); outv[3] = f2bf(a3);
    outv[4] = f2bf(a4); outv[5] = f2bf(a5); outv[6] = f2bf(a6); outv[7] = f2bf(a7);
    int slot = (lane16 & 8) | ((lane16 & 7) ^ (row & 7));
    *(s16x8*)&As2[(row * 16 + slot) * 8] = outv;
  }
  // Ws kt0 to LDS
  int4* wl = reinterpret_cast<int4*>(Ws);
  wl[tid] = wr00; wl[512 + tid] = wr01;
  const int lane = tid & 63;
  const int w = tid >> 6;             // 0..7
  const int rh = w & 3;               // 16-row band
  const int ch = w >> 2;              // column half (64 cols)
  f32x4 acc[4] = {};
#pragma unroll
  for (int kt = 0; kt < 2; ++kt) {
    __syncthreads();                  // As2 + Ws(kt) visible
#pragma unroll
    for (int kk = 0; kk < 2; ++kk) {
      int gb = kk * 4 + (lane >> 4);
      int row = rh * 16 + (lane & 15);
      s16x8 a = *(const s16x8*)&As2[(row * 16 + kt * 8 + (gb ^ (row & 7))) * 8];
#pragma unroll
      for (int fc = 0; fc < 4; ++fc) {
        int col = ch * 64 + fc * 16 + (lane & 15);
        s16x8 b = *(const s16x8*)&Ws[(col * 8 + (gb ^ (col & 7))) * 8];
        acc[fc] = __builtin_amdgcn_mfma_f32_16x16x32_bf16(a, b, acc[fc], 0, 0, 0);
      }
    }
    if (kt == 0) {
      __syncthreads();                // Ws reads done before overwrite
      wl[tid] = wr10; wl[512 + tid] = wr11;
    }
  }
  // epilogue: C/D layout col=lane&15, row=(lane>>4)*4+reg  [m89-verified]
  const int cb = lane & 15;
  const int rb = rh * 16 + (lane >> 4) * 4;
#pragma unroll
  for (int reg = 0; reg < 4; ++reg) {
    int n = n0 + rb + reg;
    if (n >= N) continue;
    long drow = GOUT ? (long)sd[n] : (long)n;
    short* cp = C16 + drow * DIM;
#pragma unroll
    for (int fc = 0; fc < 4; ++fc) {
      float x = fmaxf(acc[fc][reg], 0.f);
      cp[ch * 64 + fc * 16 + cb] = f2bf(x);
    }
  }
}

// table GEMM (256 thr): table16[w] = wemb[w] @ WtAd + adb
static __device__ __forceinline__ void tablegemm_body(
    const float* __restrict__ Af, const short* __restrict__ Wt,
    const float* __restrict__ bias, short* __restrict__ table16, short* As,
    short* Ws, int bid) {
  const int n0 = bid * 128;
  const int tid = threadIdx.x;
  f32x4 acc[2][8] = {};
#pragma unroll
  for (int kt = 0; kt < 4; ++kt) {
    __syncthreads();
#pragma unroll
    for (int p = 0; p < 4; ++p) {
      int gi = p * 256 + tid;
      int row = gi >> 3, s = gi & 7;
      int n = n0 + row;
      s16x8 v = {};
      if (n < NWORDS) {
        const float* ap = Af + (long)n * NINPK + kt * 64 + (s ^ (row & 7)) * 8;
        float4 v0 = *reinterpret_cast<const float4*>(ap);
        float4 v1 = *reinterpret_cast<const float4*>(ap + 4);
        v[0] = f2bf(v0.x); v[1] = f2bf(v0.y); v[2] = f2bf(v0.z); v[3] = f2bf(v0.w);
        v[4] = f2bf(v1.x); v[5] = f2bf(v1.y); v[6] = f2bf(v1.z); v[7] = f2bf(v1.w);
      }
      *(s16x8*)&As[(row * 8 + s) * 8] = v;
    }
    gemm_compute_epi256<false, true, false>(acc, Wt + kt * 128 * 64, bias, table16,
                                            nullptr, NWORDS, n0, As, 8, 0, Ws,
                                            kt == 3);
  }
}

// zero src-only touched hb rows (512 thr, 16B/lane)
static __device__ __forceinline__ void zzero_body(short* __restrict__ hb,
                                                  const int* __restrict__ zl,
                                                  const int* __restrict__ nzp,
                                                  int bid, int nblocks) {
  int nz = nzp[0];
  int l = threadIdx.x & 15;
  s16x8 z = {};
  for (int s = bid * 32 + (threadIdx.x >> 4); s < nz; s += nblocks * 32) {
    *reinterpret_cast<s16x8*>(&hb[(long)zl[s] * DIM + l * 8]) = z;
  }
}

// fused LSTM step k (512 thr, 4 cols/block)
static __device__ __forceinline__ void lstm_body512(
    int bid, const float* __restrict__ hxc, float* __restrict__ hxn,
    float* __restrict__ cx, const float* __restrict__ Wih,
    const float* __restrict__ Whh, const float* __restrict__ bih,
    const float* __restrict__ bhh, const int* __restrict__ meta,
    short* __restrict__ WtBase, int k, float* wi, float* wh) {
  int tid = threadIdx.x;
  int i = bid >> 5;
  int j4 = bid & 31;
  int jl = tid >> 7;
  int r = tid & 127;
  int j = j4 * 4 + jl;
  float* wiL = wi + jl * 512;
  float* whL = wh + jl * 512;
#pragma unroll
  for (int g4 = 0; g4 < 4; ++g4) {
    wiL[g4 * 128 + r] = Wih[((long)i * 512 + g4 * 128 + j) * DIM + r];
    whL[g4 * 128 + r] = Whh[((long)i * 512 + g4 * 128 + j) * DIM + r];
  }
  __syncthreads();
  const float4* x4 = reinterpret_cast<const float4*>(hxc + ((long)i * DIM + r) * DIM);
  float a0 = 0, a1 = 0, a2 = 0, a3 = 0, b0 = 0, b1 = 0, b2 = 0, b3 = 0;
#pragma unroll 4
  for (int k4 = 0; k4 < 32; ++k4) {
    float4 xv = x4[k4];
    const float* vp = &xv.x;
#pragma unroll
    for (int q = 0; q < 4; ++q) {
      int kk = k4 * 4 + q;
      float xs = vp[q];
      a0 = fmaf(xs, wiL[kk], a0);       a1 = fmaf(xs, wiL[128 + kk], a1);
      a2 = fmaf(xs, wiL[256 + kk], a2); a3 = fmaf(xs, wiL[384 + kk], a3);
      b0 = fmaf(xs, whL[kk], b0);       b1 = fmaf(xs, whL[128 + kk], b1);
      b2 = fmaf(xs, whL[256 + kk], b2); b3 = fmaf(xs, whL[384 + kk], b3);
    }
  }
  int cbi = i * 512 + j;
  float g0i = a0 + bih[cbi] + bhh[cbi];
  float g0f = a1 + bih[cbi + 128] + bhh[cbi + 128];
  float g0g = a2 + bih[cbi + 256] + bhh[cbi + 256];
  float g0o = a3 + bih[cbi + 384] + bhh[cbi + 384];
  float g1i = g0i + b0, g1f = g0f + b1, g1g = g0g + b2, g1o = g0o + b3;
  int idx = i * 16384 + r * 128 + j;
  float c0v = cx[idx];
  float c_zero = sigm(g0i) * tanhf(g0g);
  float h_zero = sigm(g0o) * tanhf(c_zero);
  float c_st = sigm(g1f) * c0v + sigm(g1i) * tanhf(g1g);
  float h_st = sigm(g1o) * tanhf(c_st);
  int first = meta[8 + k];
  int has = meta[k] > 0;
  float hi_v = first ? h_st : h_zero;
  float ci_v = first ? c0v : c_zero;
  float xj = reinterpret_cast<const float*>(x4)[j];
  float hnew = has ? hi_v : xj;
  float cnew = has ? ci_v : c0v;
  hxn[idx] = hnew;
  cx[idx] = cnew;
  short* Wt = WtBase + i * 16384;
  int kb = r >> 6, g = (r >> 3) & 7, jj = r & 7;
  Wt[((kb * DIM + j) * 8 + (g ^ (j & 7))) * 8 + jj] = f2bf(hnew);
}

// ============ kernels ============

// setup0: init state/hist/flags/meta/keys + adaptW bf16 tiles
__global__ void k_setup0(const float* __restrict__ gcn, float* __restrict__ hxA,
                         float* __restrict__ cx, int* __restrict__ meta,
                         unsigned* __restrict__ keys, int* __restrict__ hist,
                         unsigned* __restrict__ flagbits,
                         const float* __restrict__ adW, short* __restrict__ WtAd) {
  int bid = blockIdx.x;
  int tid = threadIdx.x;
  if (bid < B_INITP) {
    int i = bid * 256 + tid;
    if (i < LLAYERS * DIM * DIM) { hxA[i] = gcn[i]; cx[i] = 0.f; }
    if (i < BGRAPH * DIM) keys[i] = 0u;
    if (i < 64) meta[i] = 0;
    if (i < NBINS) hist[i] = 0;
    if (i < (NBINS + 31) / 32) flagbits[i] = 0u;
  } else {
    int idx = (bid - B_INITP) * 256 + tid;  // < 4096
    int g = idx & 7;
    int c = (idx >> 3) & 127;
    int kb = idx >> 10;
    s16x8 s;
#pragma unroll
    for (int j = 0; j < 8; ++j) s[j] = f2bf(adW[(long)(kb * 64 + g * 8 + j) * DIM + c]);
    *(s16x8*)&WtAd[(((long)kb * DIM + c) * 8 + (g ^ (c & 7))) * 8] = s;
  }
}

// hist/flag atomics + table GEMM (fp32 wemb direct), 256 thr
__global__ __launch_bounds__(256) void k_histg(
    const int* __restrict__ et, const int* __restrict__ src,
    const int* __restrict__ dst, int* __restrict__ hist,
    unsigned* __restrict__ flagbits, const float* __restrict__ wemb,
    const short* __restrict__ WtAd, const float* __restrict__ adb,
    short* __restrict__ table16) {
  __shared__ short As[128 * 64];
  __shared__ short Ws[128 * 64];
  int bid = blockIdx.x;
  if (bid < B_HIST) {
    int e = bid * 256 + threadIdx.x;
    if (e < E_EDGES) {
      int t = et[e];
      atomicAdd(&hist[t * N_NODES + dst[e]], 1);
      int fs = t * N_NODES + src[e];
      atomicOr(&flagbits[fs >> 5], 1u << (fs & 31));
    }
  } else {
    tablegemm_body(wemb, WtAd, adb, table16, As, Ws, bid - B_HIST);
  }
}

// fused 2-level exclusive scan: hist values, nonempty indicator, z indicator.
// bsum arrays stay RAW (per-block sums); scan3seg re-scans them locally.
__global__ void k_scan1b(const int* __restrict__ hist,
                         const unsigned* __restrict__ flagbits,
                         int* __restrict__ scanA, int* __restrict__ scanB,
                         int* __restrict__ scanC, int* __restrict__ bsumA,
                         int* __restrict__ bsumB, int* __restrict__ bsumC) {
  __shared__ int shA[256], shB[256], shC[256];
  int b0 = blockIdx.x * 1024;
  int tid = threadIdx.x;
  int v[4], w[4], z[4];
  int sA = 0, sB = 0, sC = 0;
#pragma unroll
  for (int q = 0; q < 4; ++q) {
    int i = b0 + tid * 4 + q;
    int c = (i < NBINS) ? hist[i] : 0;
    int fl = (i < NBINS) ? (int)((flagbits[i >> 5] >> (i & 31)) & 1u) : 0;
    v[q] = c; w[q] = (c > 0) ? 1 : 0; z[q] = (fl && c == 0) ? 1 : 0;
    sA += c; sB += w[q]; sC += z[q];
  }
  shA[tid] = sA; shB[tid] = sB; shC[tid] = sC;
  __syncthreads();
  for (int off = 1; off < 256; off <<= 1) {
    int xA = (tid >= off) ? shA[tid - off] : 0;
    int xB = (tid >= off) ? shB[tid - off] : 0;
    int xC = (tid >= off) ? shC[tid - off] : 0;
    __syncthreads();
    shA[tid] += xA; shB[tid] += xB; shC[tid] += xC;
    __syncthreads();
  }
  int exA = shA[tid] - sA, exB = shB[tid] - sB, exC = shC[tid] - sC;
#pragma unroll
  for (int q = 0; q < 4; ++q) {
    int i = b0 + tid * 4 + q;
    if (i < NBINS) { scanA[i] = exA; scanB[i] = exB; scanC[i] = exC; }
    exA += v[q]; exB += w[q]; exC += z[q];
  }
  if (tid == 255) {
    bsumA[blockIdx.x] = shA[255];
    bsumB[blockIdx.x] = shB[255];
    bsumC[blockIdx.x] = shC[255];
  }
}

// scan finalize + segment build + meta (scanA/B/C immutable, cursor -> scanD)
__global__ __launch_bounds__(256) void k_scan3seg(
    const int* __restrict__ scanA, const int* __restrict__ bsumA,
    const int* __restrict__ scanB, const int* __restrict__ bsumB,
    const int* __restrict__ scanC, const int* __restrict__ bsumC,
    const int* __restrict__ hist, const unsigned* __restrict__ flagbits,
    int* __restrict__ scanD, int* __restrict__ segdst, int* __restrict__ segstart,
    int* __restrict__ seglen, int* __restrict__ rowof, int* __restrict__ zlist,
    int* __restrict__ meta) {
  __shared__ int sA[512], sB[512], sC[512];
  int tid = threadIdx.x;
  for (int q = tid; q < 512; q += 256) {
    sA[q] = (q < NB) ? bsumA[q] : 0;
    sB[q] = (q < NB) ? bsumB[q] : 0;
    sC[q] = (q < NB) ? bsumC[q] : 0;
  }
  __syncthreads();
  for (int off = 1; off < 512; off <<= 1) {
    int q0 = tid, q1 = tid + 256;
    int a0 = (q0 >= off) ? sA[q0 - off] : 0, b0 = (q0 >= off) ? sB[q0 - off] : 0,
        c0 = (q0 >= off) ? sC[q0 - off] : 0;
    int a1 = (q1 >= off) ? sA[q1 - off] : 0, b1 = (q1 >= off) ? sB[q1 - off] : 0,
        c1 = (q1 >= off) ? sC[q1 - off] : 0;
    __syncthreads();
    sA[q0] += a0; sB[q0] += b0; sC[q0] += c0;
    sA[q1] += a1; sB[q1] += b1; sC[q1] += c1;
    __syncthreads();
  }
  int i = blockIdx.x * 256 + tid;
  if (i < NBINS) {
    int blk = i >> 10;
    int eAx = blk ? sA[blk - 1] : 0;
    int eBx = blk ? sB[blk - 1] : 0;
    int eCx = blk ? sC[blk - 1] : 0;
    int t = i / N_NODES;
    int tb = t * N_NODES;
    int blkT = tb >> 10;
    int vA = scanA[i] + eAx;
    scanD[i] = vA;
    int c = hist[i];
    if (c > 0) {
      int baseB = scanB[tb] + (blkT ? sB[blkT - 1] : 0);
      int sidx = scanB[i] + eBx - baseB;
      long sb = (long)tb + sidx;
      segdst[sb] = i - tb;
      segstart[sb] = vA;
      seglen[sb] = c;
      rowof[i] = sidx;
    } else {
      rowof[i] = -1;
      if ((flagbits[i >> 5] >> (i & 31)) & 1u) {
        int baseC = scanC[tb] + (blkT ? sC[blkT - 1] : 0);
        int zr = scanC[i] + eCx - baseC;
        zlist[(long)tb + zr] = i - tb;
      }
    }
  }
  if (blockIdx.x == 0 && tid == 0) {
    int loA[TSTEPS + 1], loB[TSTEPS + 1], loC[TSTEPS + 1];
    for (int t = 0; t < TSTEPS; ++t) {
      int ib = t * N_NODES, blk = ib >> 10;
      loA[t] = scanA[ib] + (blk ? sA[blk - 1] : 0);
      loB[t] = scanB[ib] + (blk ? sB[blk - 1] : 0);
      loC[t] = scanC[ib] + (blk ? sC[blk - 1] : 0);
    }
    loA[TSTEPS] = sA[NB - 1]; loB[TSTEPS] = sB[NB - 1]; loC[TSTEPS] = sC[NB - 1];
    int f = 0;
    for (int t = 0; t < TSTEPS; ++t) {
      int cnt = loA[t + 1] - loA[t];
      meta[t] = cnt;
      meta[8 + t] = f; f |= (cnt > 0);
      meta[32 + t] = loB[t + 1] - loB[t];   // segcnt
      meta[40 + t] = loC[t + 1] - loC[t];   // zcnt
    }
  }
}

// setup1 (512 thr): place edges (2/thread) + embed gather + lstm(0)
__global__ __launch_bounds__(512) void k_setup1(
    const int* __restrict__ et, const int* __restrict__ src,
    const int* __restrict__ dst, const float* __restrict__ ew,
    int* __restrict__ scanD, int2* __restrict__ sedge,
    const short* __restrict__ table16, const int* __restrict__ wid,
    short* __restrict__ hb, const float* __restrict__ hxA, float* __restrict__ hxB,
    float* __restrict__ cx, const float* __restrict__ Wih,
    const float* __restrict__ Whh, const float* __restrict__ bih,
    const float* __restrict__ bhh, const int* __restrict__ meta,
    short* __restrict__ WtT) {
  __shared__ float lb[4096];
  int bid = blockIdx.x;
  int tid = threadIdx.x;
  if (bid < B_PLACE2) {
    int e0 = bid * 1024 + tid;
    int e1 = e0 + 512;
    bool ok0 = e0 < E_EDGES, ok1 = e1 < E_EDGES;
    int t0 = ok0 ? et[e0] : 0, t1 = ok1 ? et[e1] : 0;
    int d0 = ok0 ? dst[e0] : 0, d1 = ok1 ? dst[e1] : 0;
    int s0 = ok0 ? src[e0] : 0, s1 = ok1 ? src[e1] : 0;
    float w0 = ok0 ? ew[e0] : 0.f, w1 = ok1 ? ew[e1] : 0.f;
    int p0 = ok0 ? atomicAdd(&scanD[t0 * N_NODES + d0], 1) : 0;
    int p1 = ok1 ? atomicAdd(&scanD[t1 * N_NODES + d1], 1) : 0;
    if (ok0) sedge[p0] = make_int2(s0, __float_as_int(w0));
    if (ok1) sedge[p1] = make_int2(s1, __float_as_int(w1));
  } else if (bid < B_PLACE2 + B_EMBED) {
    int l = tid & 15;
    for (int n = (bid - B_PLACE2) * 32 + (tid >> 4); n < N_NODES; n += B_EMBED * 32) {
      *reinterpret_cast<s16x8*>(&hb[(long)n * DIM + l * 8]) =
          *reinterpret_cast<const s16x8*>(&table16[(long)wid[n] * DIM + l * 8]);
    }
  } else {
    lstm_body512(bid - B_PLACE2 - B_EMBED, hxA, hxB, cx, Wih, Whh, bih, bhh, meta,
                 WtT, 0, lb, lb + 2048);
  }
}

// loop launch A (512 thr): fused scat0+gemm0 ∥ lstm(t+1)
__global__ __launch_bounds__(512) void k_A(
    const int* __restrict__ ss, const int* __restrict__ sl,
    const int2* __restrict__ sedge, const short* __restrict__ hb,
    const short* __restrict__ Wt0, short* __restrict__ P2b,
    const int* __restrict__ nsegp, const float* __restrict__ hxc,
    float* __restrict__ hxn, float* __restrict__ cx,
    const float* __restrict__ Wih, const float* __restrict__ Whh,
    const float* __restrict__ bih, const float* __restrict__ bhh,
    const int* __restrict__ meta, short* __restrict__ WtNext, int k) {
  __shared__ short As2[64 * 128];
  __shared__ short Ws[128 * 64];
  int bid = blockIdx.x;
  if (bid < GB64) {
    fusedgemm64<false, false>(ss, sl, sedge, hb, nullptr, Wt0, P2b, nullptr,
                              nsegp, As2, Ws, bid);
  } else if (k < TSTEPS) {
    float* lb = (float*)As2;
    lstm_body512(bid - GB64, hxc, hxn, cx, Wih, Whh, bih, bhh, meta, WtNext, k,
                 lb, lb + 2048);
  }
}

// loop launch B (512 thr): fused scat1+gemm1 ∥ zzero
__global__ __launch_bounds__(512) void k_B(
    const int* __restrict__ ss, const int* __restrict__ sl,
    const int2* __restrict__ sedge, const short* __restrict__ P2b,
    const int* __restrict__ ro, const short* __restrict__ Wt1,
    short* __restrict__ hb, const int* __restrict__ sd,
    const int* __restrict__ nsegp, const int* __restrict__ zl,
    const int* __restrict__ nzp) {
  __shared__ short As2[64 * 128];
  __shared__ short Ws[128 * 64];
  int bid = blockIdx.x;
  if (bid < GB64) {
    fusedgemm64<true, true>(ss, sl, sedge, P2b, ro, Wt1, hb, sd, nsegp,
                            As2, Ws, bid);
  } else {
    zzero_body(hb, zl, nzp, bid - GB64, B_ZZ);
  }
}

// segment max: vectorized 16B loads, LDS tree reduce, atomicMax only, no fences
__global__ __launch_bounds__(256) void k_segmax(
    const short* __restrict__ hb, const int* __restrict__ gid,
    unsigned* __restrict__ keys) {
  __shared__ float red[256 * 8];
  int tid = threadIdx.x;
  int c = tid & 15;
  int r = tid >> 4;
  int n0 = blockIdx.x * 128;
  int nend = min(n0 + 128, N_NODES);
  float m[8];
#pragma unroll
  for (int j = 0; j < 8; ++j) m[j] = -INFINITY;
  if (gid[n0] == gid[nend - 1]) {
    int g = gid[n0];
#pragma unroll
    for (int it = 0; it < 8; ++it) {
      int n = n0 + it * 16 + r;
      if (n < N_NODES) {
        s16x8 v = *(const s16x8*)&hb[(long)n * DIM + c * 8];
#pragma unroll
        for (int j = 0; j < 8; ++j) m[j] = fmaxf(m[j], bf2f(v[j]));
      }
    }
#pragma unroll
    for (int j = 0; j < 8; ++j) red[tid * 8 + j] = m[j];
    __syncthreads();
    for (int off = 8; off >= 1; off >>= 1) {
      if (r < off) {
#pragma unroll
        for (int j = 0; j < 8; ++j)
          red[tid * 8 + j] = fmaxf(red[tid * 8 + j], red[(tid + off * 16) * 8 + j]);
      }
      __syncthreads();
    }
    if (r == 0) {
#pragma unroll
      for (int j = 0; j < 8; ++j)
        atomicMax(&keys[(long)g * DIM + c * 8 + j], fenc(red[tid * 8 + j]));
    }
  } else {
    int curg = -1;
#pragma unroll
    for (int it = 0; it < 8; ++it) {
      int n = n0 + it * 16 + r;
      if (n >= N_NODES) break;
      int g = gid[n];
      if (g != curg) {
        if (curg >= 0) {
#pragma unroll
          for (int j = 0; j < 8; ++j)
            atomicMax(&keys[(long)curg * DIM + c * 8 + j], fenc(m[j]));
        }
        curg = g;
#pragma unroll
        for (int j = 0; j < 8; ++j) m[j] = -INFINITY;
      }
      s16x8 v = *(const s16x8*)&hb[(long)n * DIM + c * 8];
#pragma unroll
      for (int j = 0; j < 8; ++j) m[j] = fmaxf(m[j], bf2f(v[j]));
    }
    if (curg >= 0) {
#pragma unroll
      for (int j = 0; j < 8; ++j)
        atomicMax(&keys[(long)curg * DIM + c * 8 + j], fenc(m[j]));
    }
  }
}

// final: logits, probs, BCE loss
__global__ void k_final(const unsigned* __restrict__ keys, const float* __restrict__ outW,
                        const float* __restrict__ outB, const float* __restrict__ y,
                        float* __restrict__ out) {
  __shared__ float lt[BGRAPH];
  int tid = threadIdx.x;
  int b = tid >> 2, l4 = tid & 3;
  float s = 0.f;
  for (int d = l4; d < DIM; d += 4) {
    float v = fdec(keys[(long)b * DIM + d]);
    if (!isfinite(v)) v = 0.f;
    s += v * outW[d];
  }
  s += __shfl_down(s, 1);
  s += __shfl_down(s, 2);
  if (l4 == 0) {
    float l = s + outB[0];
    out[1 + b] = 1.f / (1.f + expf(-l));
    lt[b] = fmaxf(l, 0.f) - l * y[b] + log1pf(expf(-fabsf(l)));
  }
  __syncthreads();
  if (tid == 0) {
    float acc = 0.f;
    for (int i = 0; i < BGRAPH; ++i) acc += lt[i];
    out[0] = acc / (float)BGRAPH;
  }
}

extern "C" void kernel_launch(void* const* d_in, const int* in_sizes, int n_in,
                              void* d_out, int out_size, void* d_ws, size_t ws_size,
                              hipStream_t stream) {
  const int* word_ids = (const int*)d_in[0];
  const int* src = (const int*)d_in[1];
  const int* dst = (const int*)d_in[2];
  const int* et = (const int*)d_in[3];
  const float* ew = (const float*)d_in[4];
  const int* gid = (const int*)d_in[5];
  const float* y = (const float*)d_in[6];
  const float* wemb = (const float*)d_in[7];
  const float* adW = (const float*)d_in[8];
  const float* adb = (const float*)d_in[9];
  const float* gcn = (const float*)d_in[10];
  const float* Wih = (const float*)d_in[11];
  const float* Whh = (const float*)d_in[12];
  const float* bih = (const float*)d_in[13];
  const float* bhh = (const float*)d_in[14];
  const float* outW = (const float*)d_in[15];
  const float* outB = (const float*)d_in[16];
  float* out = (float*)d_out;

  char* ws = (char*)d_ws;
  const long ND = (long)N_NODES * DIM;
  short* hb = (short*)ws;       ws += ND * 2;
  short* P2b = (short*)ws;      ws += ND * 2;
  float* hxA = (float*)ws;      ws += LLAYERS * DIM * DIM * 4;
  float* hxB = (float*)ws;      ws += LLAYERS * DIM * DIM * 4;
  float* cx = (float*)ws;       ws += LLAYERS * DIM * DIM * 4;
  int* meta = (int*)ws;         ws += 64 * 4;
  unsigned* keys = (unsigned*)ws; ws += BGRAPH * DIM * 4;
  int* hist = (int*)ws;         ws += (long)NBINS * 4;
  int* scanA = (int*)ws;        ws += (long)NBINS * 4;
  int* scanB = (int*)ws;        ws += (long)NBINS * 4;
  int* scanC = (int*)ws;        ws += (long)NBINS * 4;
  int* scanD = (int*)ws;        ws += (long)NBINS * 4;
  int* bsumA = (int*)ws;        ws += ((NB + 63) & ~63) * 4;
  int* bsumB = (int*)ws;        ws += ((NB + 63) & ~63) * 4;
  int* bsumC = (int*)ws;        ws += ((NB + 63) & ~63) * 4;
  int* rowof = (int*)ws;        ws += (long)NBINS * 4;
  int* segdst = (int*)ws;       ws += (long)NBINS * 4;
  int* segstart = (int*)ws;     ws += (long)NBINS * 4;
  int* seglen = (int*)ws;       ws += (long)NBINS * 4;
  int* zlist = (int*)ws;        ws += (long)NBINS * 4;
  int2* sedge = (int2*)ws;      ws += (long)E_EDGES * 8;
  unsigned* flagbits = (unsigned*)ws; ws += ((NBINS + 31) / 32 + 64) * 4;
  short* table16 = (short*)ws;  ws += (long)NWORDS * DIM * 2;
  short* WtAd = (short*)ws;     ws += 4L * DIM * 64 * 2;
  short* WtT = (short*)ws;      ws += 7L * 2 * 16384 * 2;  // [t][layer] bf16 tiles

  // ---- setup (5 launches) ----
  k_setup0<<<B_INITP + B_PREP, 256, 0, stream>>>(gcn, hxA, cx, meta, keys, hist,
                                                 flagbits, adW, WtAd);
  k_histg<<<B_HIST + B_TGEMM, 256, 0, stream>>>(et, src, dst, hist, flagbits,
                                                wemb, WtAd, adb, table16);
  k_scan1b<<<NB, 256, 0, stream>>>(hist, flagbits, scanA, scanB, scanC,
                                   bsumA, bsumB, bsumC);
  k_scan3seg<<<B_INITP, 256, 0, stream>>>(scanA, bsumA, scanB, bsumB, scanC, bsumC,
                                          hist, flagbits, scanD, segdst, segstart,
                                          seglen, rowof, zlist, meta);
  k_setup1<<<B_PLACE2 + B_EMBED + B_LSTM5, 512, 0, stream>>>(
      et, src, dst, ew, scanD, sedge, table16, word_ids, hb, hxA, hxB, cx,
      Wih, Whh, bih, bhh, meta, WtT);

  // ---- t-loop (2 launches per step) ----
  for (int t = 0; t < TSTEPS; ++t) {
    const int* nsegp = &meta[32 + t];
    const int* nzp = &meta[40 + t];
    const int* ss = segstart + (long)t * N_NODES;
    const int* sl = seglen + (long)t * N_NODES;
    const int* sd = segdst + (long)t * N_NODES;
    const int* ro = rowof + (long)t * N_NODES;
    const int* zl = zlist + (long)t * N_NODES;
    int k = t + 1;  // prefetched lstm step
    const float* hxc = (k & 1) ? hxB : hxA;
    float* hxn = (k & 1) ? hxA : hxB;
    k_A<<<GB64 + B_LSTM5, 512, 0, stream>>>(
        ss, sl, sedge, hb, WtT + (long)t * 2 * 16384, P2b, nsegp,
        hxc, hxn, cx, Wih, Whh, bih, bhh, meta, WtT + (long)k * 2 * 16384, k);
    k_B<<<GB64 + B_ZZ, 512, 0, stream>>>(
        ss, sl, sedge, P2b, ro, WtT + ((long)t * 2 + 1) * 16384, hb, sd, nsegp,
        zl, nzp);
  }

  k_segmax<<<B_SEGMAX, 256, 0, stream>>>(hb, gid, keys);
  k_final<<<1, 64, 0, stream>>>(keys, outW, outB, y, out);
}